// Round 3
// baseline (2389.702 us; speedup 1.0000x reference)
//
#include <hip/hip_runtime.h>

#define SS 8
#define NN 5000
#define NNSQ 25000000
#define DD 128
#define RB 8          // rows per block
#define JS 4          // column splits (partials)
#define JT 128        // tile columns
#define NT 40         // tiles total (last tile ragged: 8 cols)
#define TPB 10        // tiles per block
#define QS 132        // qv row stride (floats)
#define RG 625        // row groups

typedef float f4 __attribute__((ext_vector_type(4)));

__global__ __launch_bounds__(256, 2)
void diffuse_spmm(const float* __restrict__ theta,
                  const float* __restrict__ Tm,
                  const float* __restrict__ x,
                  const float* __restrict__ am,
                  float* __restrict__ ws)
{
    __shared__ float qv[2][RB * QS];       // double-buffered q tile
    __shared__ float red[3 * RB * 128];    // cross-wave reduction buffer

    const int t  = threadIdx.x;
    const int rg = blockIdx.x % RG;
    const int js = blockIdx.x / RG;
    const int i0 = rg * RB;
    const int tile0 = js * TPB;

    // Phase A mapping
    const int ar = t >> 5;            // row 0..7
    const int aj = (t & 31) << 2;     // col quad offset
    // Phase B mapping
    const int slot = t & 31;
    const int h    = t >> 5;          // j-subgroup (16 cols each)
    const int d0   = slot << 2;

    float th[SS];
#pragma unroll
    for (int s = 0; s < SS; ++s) th[s] = theta[s];

    f4 sa;
    f4 st[SS];
    bool svalid = false;

    auto stage = [&](int tt) {
        const int j = tt * JT + aj;
        svalid = (j < NN);
        if (svalid) {
            size_t off = (size_t)(i0 + ar) * NN + j;
            sa = __builtin_nontemporal_load((const f4*)(am + off));
#pragma unroll
            for (int s = 0; s < SS; ++s)
                st[s] = __builtin_nontemporal_load((const f4*)(Tm + (size_t)s * NNSQ + off));
        }
    };

    auto qwrite = [&](int nb) {
        f4 q;
        if (svalid) {
            f4 ssum = st[0] * th[0];
#pragma unroll
            for (int s = 1; s < SS; ++s) ssum += st[s] * th[s];
            q = sa * ssum;
        } else {
            q = (f4)(0.0f);
        }
        *(f4*)&qv[nb][ar * QS + aj] = q;
    };

    f4 xvr[3][4];   // current tile, qq = 1..3

    auto xload0 = [&](f4 (&dst)[4], int tt) {     // qq = 0 rows of tile tt
        const int j = tt * JT + (h << 4);
#pragma unroll
        for (int jo = 0; jo < 4; ++jo) {
            if (j + jo < NN) dst[jo] = *(const f4*)(x + (size_t)(j + jo) * DD + d0);
            else             dst[jo] = (f4)(0.0f);
        }
    };
    auto xloadr = [&](int tt) {                   // qq = 1..3 rows of tile tt
        const int jb = tt * JT + (h << 4);
#pragma unroll
        for (int qq = 1; qq < 4; ++qq)
#pragma unroll
            for (int jo = 0; jo < 4; ++jo) {
                const int j = jb + (qq << 2) + jo;
                if (j < NN) xvr[qq - 1][jo] = *(const f4*)(x + (size_t)j * DD + d0);
                else        xvr[qq - 1][jo] = (f4)(0.0f);
            }
    };

    f4 acc[RB];
#pragma unroll
    for (int r = 0; r < RB; ++r) acc[r] = (f4)(0.0f);

    f4 xA[4], xB[4];    // qq=0 double buffer (explicit regs, static indexing)

    // prologue: x(qq0, tile0) + stage(tile0), publish qv[0]
    xload0(xA, tile0);
    stage(tile0);
    qwrite(0);
    __syncthreads();

    // loop body: x(qq1..3, k) -> x(qq0, k+1) -> stage(k+1) -> Phase B(k) -> qwrite -> barrier
    auto body = [&](int k, f4 (&x0cur)[4], f4 (&x0nxt)[4]) {
        const int tt = tile0 + k;
        const int j0jj = 0; (void)j0jj;
        xloadr(tt);                               // issued FIRST (before stage -> no FIFO drain)
        if (k + 1 < TPB) xload0(x0nxt, tt + 1);
        __builtin_amdgcn_sched_barrier(0);
        if (k + 1 < TPB) stage(tt + 1);           // HBM loads last in FIFO
        __builtin_amdgcn_sched_barrier(0);

        const float* qp = &qv[k & 1][0];          // LDS runtime index: fine
#pragma unroll
        for (int qq = 0; qq < 4; ++qq) {
            const int jj = (h << 4) + (qq << 2);
            const f4* xp = (qq == 0) ? x0cur : xvr[qq - 1];
#pragma unroll
            for (int r = 0; r < RB; ++r) {
                f4 q = *(const f4*)&qp[r * QS + jj];
                acc[r] += q.x * xp[0];
                acc[r] += q.y * xp[1];
                acc[r] += q.z * xp[2];
                acc[r] += q.w * xp[3];
            }
        }

        if (k + 1 < TPB) {
            qwrite((k & 1) ^ 1);                  // vmcnt(0) drains stage; hidden by Phase B
            __syncthreads();
        }
    };

#pragma unroll
    for (int k = 0; k < TPB; k += 2) {
        body(k,     xA, xB);
        body(k + 1, xB, xA);
    }

    // reduce h-pairs within wave, then cross-wave via LDS
#pragma unroll
    for (int r = 0; r < RB; ++r)
#pragma unroll
        for (int c = 0; c < 4; ++c)
            acc[r][c] += __shfl_xor(acc[r][c], 32);

    const int w    = t >> 6;
    const int lane = t & 63;
    if (w > 0 && lane < 32) {
#pragma unroll
        for (int r = 0; r < RB; ++r)
            *(f4*)&red[((w - 1) * RB + r) * 128 + d0] = acc[r];
    }
    __syncthreads();
    if (w == 0 && lane < 32) {
#pragma unroll
        for (int r = 0; r < RB; ++r) {
            f4 v = acc[r];
#pragma unroll
            for (int p = 0; p < 3; ++p)
                v += *(const f4*)&red[(p * RB + r) * 128 + d0];
            *(f4*)&ws[(((size_t)js * RG + rg) * RB + r) * DD + d0] = v;
        }
    }
}

// Kernel 2: out[i,:] = PReLU(sum_js partial[js][i,:]) @ W^T + b
__global__ __launch_bounds__(256, 2)
void prelu_linear(const float* __restrict__ alpha,
                  const float* __restrict__ W,
                  const float* __restrict__ b,
                  const float* __restrict__ ws,
                  float* __restrict__ out)
{
    __shared__ float Wt[128 * 129];
    __shared__ float p[16 * 128];
    const int t  = threadIdx.x;
    const int i0 = blockIdx.x * 16;

#pragma unroll
    for (int it = 0; it < 16; ++it) {
        int f  = (it * 256 + t) * 4;
        int d  = f >> 7;
        int kk = f & 127;
        f4 w4 = *(const f4*)(W + f);
        Wt[(kk + 0) * 129 + d] = w4.x;
        Wt[(kk + 1) * 129 + d] = w4.y;
        Wt[(kk + 2) * 129 + d] = w4.z;
        Wt[(kk + 3) * 129 + d] = w4.w;
    }

#pragma unroll
    for (int it = 0; it < 2; ++it) {
        int fi  = it * 256 + t;
        int row = i0 + (fi >> 5);
        int dc  = (fi & 31) << 2;
        if (row < NN) {
            size_t base = (size_t)row * DD + dc;
            f4 v = *(const f4*)(ws + base);
            v += *(const f4*)(ws + base + (size_t)1 * RG * RB * DD);
            v += *(const f4*)(ws + base + (size_t)2 * RG * RB * DD);
            v += *(const f4*)(ws + base + (size_t)3 * RG * RB * DD);
            f4 al = *(const f4*)(alpha + dc);
            f4 pv;
            pv.x = v.x >= 0.f ? v.x : al.x * v.x;
            pv.y = v.y >= 0.f ? v.y : al.y * v.y;
            pv.z = v.z >= 0.f ? v.z : al.z * v.z;
            pv.w = v.w >= 0.f ? v.w : al.w * v.w;
            *(f4*)&p[(row - i0) * 128 + dc] = pv;
        }
    }
    __syncthreads();

    const int d  = t & 127;
    const int rq = t >> 7;
    const float bv = b[d];
    float acc[8];
#pragma unroll
    for (int ri = 0; ri < 8; ++ri) acc[ri] = 0.f;
#pragma unroll 8
    for (int k = 0; k < 128; ++k) {
        float wv = Wt[k * 129 + d];
#pragma unroll
        for (int ri = 0; ri < 8; ++ri)
            acc[ri] += p[(rq * 8 + ri) * 128 + k] * wv;
    }
#pragma unroll
    for (int ri = 0; ri < 8; ++ri) {
        int row = i0 + rq * 8 + ri;
        if (row < NN) out[(size_t)row * DD + d] = acc[ri] + bv;
    }
}

extern "C" void kernel_launch(void* const* d_in, const int* in_sizes, int n_in,
                              void* d_out, int out_size, void* d_ws, size_t ws_size,
                              hipStream_t stream) {
    const float* theta = (const float*)d_in[0];
    const float* T     = (const float*)d_in[1];
    const float* x     = (const float*)d_in[2];
    const float* a     = (const float*)d_in[3];
    const float* alpha = (const float*)d_in[4];
    const float* W     = (const float*)d_in[5];
    const float* b     = (const float*)d_in[6];
    float* out = (float*)d_out;
    float* ws  = (float*)d_ws;

    dim3 blk(256);
    dim3 g1(RG * JS);                 // 2500 blocks
    diffuse_spmm<<<g1, blk, 0, stream>>>(theta, T, x, a, ws);

    dim3 g2((NN + 15) / 16);          // 313 blocks
    prelu_linear<<<g2, blk, 0, stream>>>(alpha, W, b, ws, out);
}

// Round 4
// 701.309 us; speedup vs baseline: 3.4075x; 3.4075x over previous
//
#include <hip/hip_runtime.h>

#define SS 8
#define NN 5000
#define NNSQ 25000000
#define DD 128
#define RB 8          // rows per block
#define JS 4          // column splits (partials)
#define JT 128        // tile columns
#define NT 40         // tiles total (last tile ragged: 8 cols)
#define TPB 10        // tiles per block
#define QS 132        // qv row stride (floats)
#define RG 625        // row groups

typedef float f4 __attribute__((ext_vector_type(4)));

__global__ __launch_bounds__(256, 2)
void diffuse_spmm(const float* __restrict__ theta,
                  const float* __restrict__ Tm,
                  const float* __restrict__ x,
                  const float* __restrict__ am,
                  float* __restrict__ ws)
{
    __shared__ float qv[2][RB * QS];       // double-buffered q tile
    __shared__ float red[3 * RB * 128];    // cross-wave reduction buffer

    const int t  = threadIdx.x;
    const int rg = blockIdx.x % RG;
    const int js = blockIdx.x / RG;
    const int i0 = rg * RB;
    const int tile0 = js * TPB;

    // Phase A mapping: 1 item/thread (8 rows x 32 quads)
    const int ar = t >> 5;            // row 0..7
    const int aj = (t & 31) << 2;     // col quad offset
    // Phase B mapping
    const int slot = t & 31;          // d-group
    const int h    = t >> 5;          // j-subgroup (16 consecutive cols)
    const int d0   = slot << 2;

    float th[SS];
#pragma unroll
    for (int s = 0; s < SS; ++s) th[s] = theta[s];

    f4 sa;
    f4 st[SS];
    bool svalid = false;

    auto stage = [&](int tt) {
        const int j = tt * JT + aj;
        svalid = (j < NN);
        if (svalid) {
            size_t off = (size_t)(i0 + ar) * NN + j;
            sa = __builtin_nontemporal_load((const f4*)(am + off));
#pragma unroll
            for (int s = 0; s < SS; ++s)
                st[s] = __builtin_nontemporal_load((const f4*)(Tm + (size_t)s * NNSQ + off));
        }
    };

    auto qwrite = [&](int nb) {
        f4 q;
        if (svalid) {
            f4 ssum = st[0] * th[0];
#pragma unroll
            for (int s = 1; s < SS; ++s) ssum += st[s] * th[s];
            q = sa * ssum;
        } else {
            q = (f4)(0.0f);
        }
        *(f4*)&qv[nb][ar * QS + aj] = q;
    };

    f4 acc[RB];
#pragma unroll
    for (int r = 0; r < RB; ++r) acc[r] = (f4)(0.0f);

    // prologue: stage + publish tile 0
    stage(tile0);
    qwrite(0);
    __syncthreads();

    for (int k = 0; k < TPB; ++k) {
        const int tt = tile0 + k;

        // ---- x loads for THIS tile, issued FIRST (before stage -> consuming
        //      them never drains the stage loads in the vmcnt FIFO) ----
        f4 xv[16];                    // static indexing only (rule #20)
        {
            const int jb = tt * JT + (h << 4);
#pragma unroll
            for (int q = 0; q < 16; ++q) {
                const int j = jb + q;
                if (j < NN) xv[q] = *(const f4*)(x + (size_t)j * DD + d0);
                else        xv[q] = (f4)(0.0f);
            }
        }
        __builtin_amdgcn_sched_barrier(0);
        // ---- next tile's T/a loads: last into the FIFO ----
        if (k + 1 < TPB) stage(tt + 1);
        __builtin_amdgcn_sched_barrier(0);

        // ---- Phase B: acc[r] += qv[r][jj] * x[jj][d0..d0+3] ----
        const float* qp = &qv[k & 1][0];
#pragma unroll
        for (int qc = 0; qc < 4; ++qc) {
#pragma unroll
            for (int r = 0; r < RB; ++r) {
                f4 q = *(const f4*)&qp[r * QS + (h << 4) + (qc << 2)];
                acc[r] += q.x * xv[qc * 4 + 0];
                acc[r] += q.y * xv[qc * 4 + 1];
                acc[r] += q.z * xv[qc * 4 + 2];
                acc[r] += q.w * xv[qc * 4 + 3];
            }
        }

        if (k + 1 < TPB) {
            qwrite((k & 1) ^ 1);      // vmcnt(0) drain of stage, hidden by Phase B
            __syncthreads();
        }
    }

    // reduce h-pairs within wave, then cross-wave via LDS
#pragma unroll
    for (int r = 0; r < RB; ++r)
#pragma unroll
        for (int c = 0; c < 4; ++c)
            acc[r][c] += __shfl_xor(acc[r][c], 32);

    const int w    = t >> 6;
    const int lane = t & 63;
    if (w > 0 && lane < 32) {
#pragma unroll
        for (int r = 0; r < RB; ++r)
            *(f4*)&red[((w - 1) * RB + r) * 128 + d0] = acc[r];
    }
    __syncthreads();
    if (w == 0 && lane < 32) {
#pragma unroll
        for (int r = 0; r < RB; ++r) {
            f4 v = acc[r];
#pragma unroll
            for (int p = 0; p < 3; ++p)
                v += *(const f4*)&red[(p * RB + r) * 128 + d0];
            *(f4*)&ws[(((size_t)js * RG + rg) * RB + r) * DD + d0] = v;
        }
    }
}

// Kernel 2: out[i,:] = PReLU(sum_js partial[js][i,:]) @ W^T + b
__global__ __launch_bounds__(256, 2)
void prelu_linear(const float* __restrict__ alpha,
                  const float* __restrict__ W,
                  const float* __restrict__ b,
                  const float* __restrict__ ws,
                  float* __restrict__ out)
{
    __shared__ float Wt[128 * 129];
    __shared__ float p[16 * 128];
    const int t  = threadIdx.x;
    const int i0 = blockIdx.x * 16;

#pragma unroll
    for (int it = 0; it < 16; ++it) {
        int f  = (it * 256 + t) * 4;
        int d  = f >> 7;
        int kk = f & 127;
        f4 w4 = *(const f4*)(W + f);
        Wt[(kk + 0) * 129 + d] = w4.x;
        Wt[(kk + 1) * 129 + d] = w4.y;
        Wt[(kk + 2) * 129 + d] = w4.z;
        Wt[(kk + 3) * 129 + d] = w4.w;
    }

#pragma unroll
    for (int it = 0; it < 2; ++it) {
        int fi  = it * 256 + t;
        int row = i0 + (fi >> 5);
        int dc  = (fi & 31) << 2;
        if (row < NN) {
            size_t base = (size_t)row * DD + dc;
            f4 v = *(const f4*)(ws + base);
            v += *(const f4*)(ws + base + (size_t)1 * RG * RB * DD);
            v += *(const f4*)(ws + base + (size_t)2 * RG * RB * DD);
            v += *(const f4*)(ws + base + (size_t)3 * RG * RB * DD);
            f4 al = *(const f4*)(alpha + dc);
            f4 pv;
            pv.x = v.x >= 0.f ? v.x : al.x * v.x;
            pv.y = v.y >= 0.f ? v.y : al.y * v.y;
            pv.z = v.z >= 0.f ? v.z : al.z * v.z;
            pv.w = v.w >= 0.f ? v.w : al.w * v.w;
            *(f4*)&p[(row - i0) * 128 + dc] = pv;
        }
    }
    __syncthreads();

    const int d  = t & 127;
    const int rq = t >> 7;
    const float bv = b[d];
    float acc[8];
#pragma unroll
    for (int ri = 0; ri < 8; ++ri) acc[ri] = 0.f;
#pragma unroll 8
    for (int k = 0; k < 128; ++k) {
        float wv = Wt[k * 129 + d];
#pragma unroll
        for (int ri = 0; ri < 8; ++ri)
            acc[ri] += p[(rq * 8 + ri) * 128 + k] * wv;
    }
#pragma unroll
    for (int ri = 0; ri < 8; ++ri) {
        int row = i0 + rq * 8 + ri;
        if (row < NN) out[(size_t)row * DD + d] = acc[ri] + bv;
    }
}

extern "C" void kernel_launch(void* const* d_in, const int* in_sizes, int n_in,
                              void* d_out, int out_size, void* d_ws, size_t ws_size,
                              hipStream_t stream) {
    const float* theta = (const float*)d_in[0];
    const float* T     = (const float*)d_in[1];
    const float* x     = (const float*)d_in[2];
    const float* a     = (const float*)d_in[3];
    const float* alpha = (const float*)d_in[4];
    const float* W     = (const float*)d_in[5];
    const float* b     = (const float*)d_in[6];
    float* out = (float*)d_out;
    float* ws  = (float*)d_ws;

    dim3 blk(256);
    dim3 g1(RG * JS);                 // 2500 blocks
    diffuse_spmm<<<g1, blk, 0, stream>>>(theta, T, x, a, ws);

    dim3 g2((NN + 15) / 16);          // 313 blocks
    prelu_linear<<<g2, blk, 0, stream>>>(alpha, W, b, ws, out);
}

// Round 5
// 232.418 us; speedup vs baseline: 10.2819x; 3.0174x over previous
//
#include <hip/hip_runtime.h>

#define SS 8
#define NN 5000
#define NNSQ 25000000
#define DD 128
#define RB 8          // rows per block
#define JS 4          // column splits (partials)
#define JT 128        // tile columns
#define TPB 10        // tiles per block
#define QS 132        // qv row stride (floats)
#define RG 625        // row groups

typedef float f4 __attribute__((ext_vector_type(4)));

typedef const __attribute__((address_space(1))) void glb_void;
typedef __attribute__((address_space(3))) void lds_void;

__device__ __forceinline__ void gld_lds16(const void* g, void* l) {
    __builtin_amdgcn_global_load_lds((glb_void*)g, (lds_void*)l, 16, 0, 0);
}

__global__ __launch_bounds__(256, 2)
void diffuse_spmm(const float* __restrict__ theta,
                  const float* __restrict__ Tm,
                  const float* __restrict__ x,
                  const float* __restrict__ am,
                  float* __restrict__ ws)
{
    // stage: [9][RB][128] floats; slices 0..7 = T slices, slice 8 = a. Single buffer.
    __shared__ float stage[9 * RB * 128];
    __shared__ float qv[2][RB * QS];       // double-buffered q tile
    __shared__ float red[3 * RB * 128];    // cross-wave reduction buffer

    const int t    = threadIdx.x;
    const int wid  = t >> 6;
    const int lane = t & 63;
    const int rg   = blockIdx.x % RG;
    const int js   = blockIdx.x / RG;
    const int i0   = rg * RB;
    const int tile0 = js * TPB;

    // stage/q-compute mapping: thread touches only rows its own wave DMA'd
    const int ar = (wid << 1) + (lane >> 5);   // row 0..7 (wave w owns rows 2w,2w+1)
    const int aj = (lane & 31) << 2;           // col quad offset 0..124
    // Phase B mapping
    const int slot = t & 31;
    const int h    = t >> 5;                   // j-subgroup (16 consecutive cols)
    const int d0   = slot << 2;

    float th[SS];
#pragma unroll
    for (int s = 0; s < SS; ++s) th[s] = theta[s];

    // DMA one tile's T/a rows into stage (no VGPR cost).
    // LDS dest is wave-uniform; lanes 0..31 -> row 2w (512 B), 32..63 -> row 2w+1.
    auto stage_dma = [&](int tt) {
        const int j = tt * JT + aj;
        if (j < NN) {                          // ragged last tile: mask lanes
            const size_t goff = (size_t)(i0 + ar) * NN + j;
#pragma unroll
            for (int s = 0; s < SS; ++s)
                gld_lds16(Tm + (size_t)s * NNSQ + goff,
                          &stage[s * (RB * 128) + (wid << 1) * 128]);
            gld_lds16(am + goff, &stage[SS * (RB * 128) + (wid << 1) * 128]);
        }
    };

    // q-compute for tile tt -> qv[n] (reads only own-wave staged rows)
    auto qcompute = [&](int tt, int n) {
        const int j = tt * JT + aj;
        const int lbase = ar * 128 + aj;
        f4 ssum = (*(const f4*)&stage[0 * (RB * 128) + lbase]) * th[0];
#pragma unroll
        for (int s = 1; s < SS; ++s)
            ssum += (*(const f4*)&stage[s * (RB * 128) + lbase]) * th[s];
        f4 av = *(const f4*)&stage[SS * (RB * 128) + lbase];
        f4 q  = av * ssum;
        if (j >= NN) q = (f4)(0.0f);           // zero cols beyond N (stale LDS)
        *(f4*)&qv[n][ar * QS + aj] = q;
    };

    f4 acc[RB];
#pragma unroll
    for (int r = 0; r < RB; ++r) acc[r] = (f4)(0.0f);

    // prologue: stage tile0, compute qv[0]
    stage_dma(tile0);
    asm volatile("s_waitcnt vmcnt(0)" ::: "memory");
    __builtin_amdgcn_sched_barrier(0);
    qcompute(tile0, 0);
    __syncthreads();

    for (int k = 0; k < TPB; ++k) {
        const int tt = tile0 + k;

        // ---- x loads for THIS tile: FIRST into the vmcnt FIFO ----
        f4 xv[16];                             // static indexing only
        {
            const int jb = tt * JT + (h << 4);
#pragma unroll
            for (int q = 0; q < 16; ++q) {
                const int j = jb + q;
                if (j < NN) xv[q] = *(const f4*)(x + (size_t)j * DD + d0);
                else        xv[q] = (f4)(0.0f);
            }
        }
        __builtin_amdgcn_sched_barrier(0);
        // ---- next tile's T/a DMA: LAST into the FIFO (0 registers) ----
        if (k + 1 < TPB) stage_dma(tt + 1);
        __builtin_amdgcn_sched_barrier(0);

        // ---- Phase B: acc[r] += qv[r][jj] * x[jj][d0..d0+3] ----
        // consuming xv waits vmcnt(9) at worst -> DMA stays in flight
        const float* qp = &qv[k & 1][0];
#pragma unroll
        for (int qc = 0; qc < 4; ++qc) {
#pragma unroll
            for (int r = 0; r < RB; ++r) {
                f4 q = *(const f4*)&qp[r * QS + (h << 4) + (qc << 2)];
                acc[r] += q.x * xv[qc * 4 + 0];
                acc[r] += q.y * xv[qc * 4 + 1];
                acc[r] += q.z * xv[qc * 4 + 2];
                acc[r] += q.w * xv[qc * 4 + 3];
            }
        }

        if (k + 1 < TPB) {
            // DMA issued ~1000+ cycles ago; drain is cheap now
            asm volatile("s_waitcnt vmcnt(0)" ::: "memory");
            __builtin_amdgcn_sched_barrier(0);
            qcompute(tt + 1, (k + 1) & 1);     // own-wave rows -> no barrier needed
            __syncthreads();                   // publish qv; orders stage reuse
        }
    }

    // reduce h-pairs within wave, then cross-wave via LDS
#pragma unroll
    for (int r = 0; r < RB; ++r)
#pragma unroll
        for (int c = 0; c < 4; ++c)
            acc[r][c] += __shfl_xor(acc[r][c], 32);

    const int w = t >> 6;
    if (w > 0 && (t & 63) < 32) {
#pragma unroll
        for (int r = 0; r < RB; ++r)
            *(f4*)&red[((w - 1) * RB + r) * 128 + d0] = acc[r];
    }
    __syncthreads();
    if (w == 0 && (t & 63) < 32) {
#pragma unroll
        for (int r = 0; r < RB; ++r) {
            f4 v = acc[r];
#pragma unroll
            for (int p = 0; p < 3; ++p)
                v += *(const f4*)&red[(p * RB + r) * 128 + d0];
            *(f4*)&ws[(((size_t)js * RG + rg) * RB + r) * DD + d0] = v;
        }
    }
}

// Kernel 2: out[i,:] = PReLU(sum_js partial[js][i,:]) @ W^T + b
__global__ __launch_bounds__(256, 2)
void prelu_linear(const float* __restrict__ alpha,
                  const float* __restrict__ W,
                  const float* __restrict__ b,
                  const float* __restrict__ ws,
                  float* __restrict__ out)
{
    __shared__ float Wt[128 * 129];
    __shared__ float p[16 * 128];
    const int t  = threadIdx.x;
    const int i0 = blockIdx.x * 16;

#pragma unroll
    for (int it = 0; it < 16; ++it) {
        int f  = (it * 256 + t) * 4;
        int d  = f >> 7;
        int kk = f & 127;
        f4 w4 = *(const f4*)(W + f);
        Wt[(kk + 0) * 129 + d] = w4.x;
        Wt[(kk + 1) * 129 + d] = w4.y;
        Wt[(kk + 2) * 129 + d] = w4.z;
        Wt[(kk + 3) * 129 + d] = w4.w;
    }

#pragma unroll
    for (int it = 0; it < 2; ++it) {
        int fi  = it * 256 + t;
        int row = i0 + (fi >> 5);
        int dc  = (fi & 31) << 2;
        if (row < NN) {
            size_t base = (size_t)row * DD + dc;
            f4 v = *(const f4*)(ws + base);
            v += *(const f4*)(ws + base + (size_t)1 * RG * RB * DD);
            v += *(const f4*)(ws + base + (size_t)2 * RG * RB * DD);
            v += *(const f4*)(ws + base + (size_t)3 * RG * RB * DD);
            f4 al = *(const f4*)(alpha + dc);
            f4 pv;
            pv.x = v.x >= 0.f ? v.x : al.x * v.x;
            pv.y = v.y >= 0.f ? v.y : al.y * v.y;
            pv.z = v.z >= 0.f ? v.z : al.z * v.z;
            pv.w = v.w >= 0.f ? v.w : al.w * v.w;
            *(f4*)&p[(row - i0) * 128 + dc] = pv;
        }
    }
    __syncthreads();

    const int d  = t & 127;
    const int rq = t >> 7;
    const float bv = b[d];
    float acc[8];
#pragma unroll
    for (int ri = 0; ri < 8; ++ri) acc[ri] = 0.f;
#pragma unroll 8
    for (int k = 0; k < 128; ++k) {
        float wv = Wt[k * 129 + d];
#pragma unroll
        for (int ri = 0; ri < 8; ++ri)
            acc[ri] += p[(rq * 8 + ri) * 128 + k] * wv;
    }
#pragma unroll
    for (int ri = 0; ri < 8; ++ri) {
        int row = i0 + rq * 8 + ri;
        if (row < NN) out[(size_t)row * DD + d] = acc[ri] + bv;
    }
}

extern "C" void kernel_launch(void* const* d_in, const int* in_sizes, int n_in,
                              void* d_out, int out_size, void* d_ws, size_t ws_size,
                              hipStream_t stream) {
    const float* theta = (const float*)d_in[0];
    const float* T     = (const float*)d_in[1];
    const float* x     = (const float*)d_in[2];
    const float* a     = (const float*)d_in[3];
    const float* alpha = (const float*)d_in[4];
    const float* W     = (const float*)d_in[5];
    const float* b     = (const float*)d_in[6];
    float* out = (float*)d_out;
    float* ws  = (float*)d_ws;

    dim3 blk(256);
    dim3 g1(RG * JS);                 // 2500 blocks
    diffuse_spmm<<<g1, blk, 0, stream>>>(theta, T, x, a, ws);

    dim3 g2((NN + 15) / 16);          // 313 blocks
    prelu_linear<<<g2, blk, 0, stream>>>(alpha, W, b, ws, out);
}